// Round 12
// baseline (160.555 us; speedup 1.0000x reference)
//
#include <hip/hip_runtime.h>
#include <math.h>

// MMD loss, fp16 MFMA. N=M=4096, D=1024, sigma^2=2025.
// Round 22: KILL THE THIRD LAUNCH. R11 post-mortem: mmd exactly as
// predicted (84us, Mfma 36%, conflicts 0) but total-mmd gap INVARIANT (~70us)
// across two completely different convert kernels and mmd durations 84-361us
// -> gap = convert ~13 + reduce ~4 + ~50us of per-kernel-boundary cost
// (dispatch gap + inter-kernel L2 writeback/invalidate of the 16.8MB
// handoff). Only reducible term: boundary count. final_reduce is fused into
// mmd WITHOUT the two known landmines (R6's single-address fp64 atomic storm;
// prior session's per-block fence = per-XCD L2 invalidate, 1.45x): 64-slot
// fp64 atomic accumulator (gsum[b&63], ~32 spread adds/slot, device-coherent
// w/o fences per G12) + vmcnt(0) ordering slot-add before counter-add +
// last-block-out: LDS flag broadcast, wave 0 reads all 64 slots with ONE
// wave-parallel lane-atomic instruction, shuffle-reduces, writes out.
// Convert zero-inits gsum/gcnt each replay. convert = R11 verbatim;
// mmd core = R7 verbatim (every structural deviation in R8/R9/R10 regressed;
// the 128^2/2-barrier TLP structure is at its ~823TF equilibrium).

typedef _Float16 f16_t;
typedef _Float16 f16x4 __attribute__((ext_vector_type(4)));
typedef _Float16 f16x8 __attribute__((ext_vector_type(8)));
typedef float floatx4 __attribute__((ext_vector_type(4)));

#define NROWS 4096
#define MROWS 4096
#define DDIM  1024
#define BM    128
#define BK    32                      // fp16 elements per K-step (64 B/row)
#define TILE  (BM * BK)               // 4096 f16 per tile (8 KB)
#define NKT   (DDIM / BK)             // 32 K-steps
#define PSTRIDE (4096 * BK)           // f16 elems per packed K-panel (256 KB)
#define NT    (NROWS / BM)            // 32 tiles per dim
#define TRI   (NT * (NT + 1) / 2)     // 528 triangular tiles
#define NBLK  (2 * TRI + NT * NT)     // 2080 blocks

// ---------------------------------------------------------------- convert
// 1024 blocks x 256 threads; block owns 8 rows (blocks 0..511 -> X,
// 512..1023 -> Y). Phase 1: wave w converts rows w*2, w*2+1 (float4/lane
// coalesced loads), stages fp16 in sh[8][1024], norm of the ROUNDED row
// shuffle-reduced in-wave. Phase 2: per iter g, wave w writes panel
// g*4+w's 8-row segment: 64 lanes x f16x4 = 512B FULLY CONTIGUOUS.
// Block 0 also zero-inits the fused-reduce accumulators (visible to mmd
// via the kernel boundary).
__global__ __launch_bounds__(256) void convert_kernel(
    const float* __restrict__ X, const float* __restrict__ Y,
    f16_t* __restrict__ Xp, f16_t* __restrict__ Yp,
    float* __restrict__ nx, float* __restrict__ ny,
    double* __restrict__ gsum, int* __restrict__ gcnt) {
    __shared__ __align__(16) f16_t sh[8][DDIM];   // 16 KB

    if (blockIdx.x == 0) {
        if (threadIdx.x < 64)       gsum[threadIdx.x] = 0.0;
        else if (threadIdx.x == 64) *gcnt = 0;
    }

    const int wave = threadIdx.x >> 6;
    const int lane = threadIdx.x & 63;
    const int bb   = blockIdx.x;
    const float* src;
    f16_t* dstp;
    float* nrm;
    int r0;
    if (bb < 512) { r0 = bb * 8;         src = X + (size_t)r0 * DDIM;
                    dstp = Xp;  nrm = nx; }
    else          { r0 = (bb - 512) * 8; src = Y + (size_t)r0 * DDIM;
                    dstp = Yp;  nrm = ny; }

    // phase 1: convert + stage + norms
    #pragma unroll
    for (int rr = 0; rr < 2; rr++) {
        const int lr = wave * 2 + rr;               // 0..7
        const float4* s4 = (const float4*)(src + (size_t)lr * DDIM);
        float s = 0.f;
        #pragma unroll
        for (int c = 0; c < 4; c++) {
            float4 v = s4[c * 64 + lane];
            f16x4 h;
            h[0] = (f16_t)v.x; h[1] = (f16_t)v.y;
            h[2] = (f16_t)v.z; h[3] = (f16_t)v.w;
            *(f16x4*)&sh[lr][c * 256 + lane * 4] = h;
            float h0 = (float)h[0], h1 = (float)h[1];
            float h2 = (float)h[2], h3 = (float)h[3];
            s += h0 * h0 + h1 * h1 + h2 * h2 + h3 * h3;
        }
        #pragma unroll
        for (int off = 32; off > 0; off >>= 1) s += __shfl_down(s, off);
        if (lane == 0) nrm[r0 + lr] = s;
    }
    __syncthreads();

    // phase 2: panel-major writeout, 512B contiguous per wave-instruction
    const int rr = (lane >> 3) & 7;                 // row within segment
    const int gr = lane & 7;                        // 8B granule within row
    #pragma unroll
    for (int g = 0; g < 8; g++) {
        const int p = g * 4 + wave;                 // panel 0..31
        *(f16x4*)(dstp + (size_t)p * PSTRIDE + (size_t)(r0 + rr) * BK + gr * 4)
            = *(const f16x4*)&sh[rr][p * 32 + gr * 4];
    }
}

// ---------------------------------------------------------------- main GEMM
__global__ __launch_bounds__(256) void mmd_mfma(
    const f16_t* __restrict__ Xp, const f16_t* __restrict__ Yp,
    const float* __restrict__ nx, const float* __restrict__ ny,
    double* __restrict__ gsum, int* __restrict__ gcnt,
    float* __restrict__ out) {
    // Split A/B tiles, each BM x BK fp16 = 8 KB. Row r of a tile stores
    // logical chunk c (16 B) at phys chunk c ^ ((r>>1)&3) -- measured 0
    // bank conflicts (R7).
    __shared__ __align__(16) f16_t ldsA[TILE];
    __shared__ __align__(16) f16_t ldsB[TILE];
    __shared__ double wred[4];
    __shared__ int lastflag;

    const int b = blockIdx.x;
    const f16_t *Ap, *Bp;             // packed panel bases (panel 0)
    const float *nA, *nB;
    int tr, tc;
    double coef;
    if (b < 2 * TRI) {
        int u = (b < TRI) ? b : b - TRI;
        int r = 0;
        while (u >= NT - r) { u -= NT - r; r++; }
        tr = r; tc = r + u;
        double w = (tr == tc) ? 1.0 : 2.0;   // off-diagonal tiles count twice
        if (b < TRI) { Ap = Xp; Bp = Xp; nA = nx; nB = nx;
                       coef = w / ((double)NROWS * (double)(NROWS - 1)); }
        else         { Ap = Yp; Bp = Yp; nA = ny; nB = ny;
                       coef = w / ((double)MROWS * (double)(MROWS - 1)); }
    } else {
        int u = b - 2 * TRI;
        tr = u >> 5; tc = u & 31;
        Ap = Xp; Bp = Yp; nA = nx; nB = ny;
        coef = -2.0 / ((double)NROWS * (double)MROWS);
    }

    const int t    = threadIdx.x;
    const int wave = t >> 6;            // 0..3; waves 2x2: wm=wave>>1, wn=wave&1
    const int lane = t & 63;
    const int wm   = wave >> 1;
    const int wn   = wave & 1;

    // staging: 16 glds instrs (2 tiles x 8 row-groups of 16 rows); wave w
    // issues instrs w*4 .. w*4+3. Per instr: 16 rows x 64B = CONTIGUOUS 1KB
    // in the packed panel. glds writes linearly: lane l -> row lr=l>>2,
    // phys chunk l&3; lane fetches global chunk (l&3)^((l>>3)&3) so phys
    // chunk p of row r holds logical p^((r>>1)&3).
    const int lr = lane >> 2;           // 0..15 within row-group
    const int lc = (lane & 3) ^ ((lane >> 3) & 3);
    const f16_t* gsrc[4];
    f16_t* ldst[4];
    #pragma unroll
    for (int i = 0; i < 4; i++) {
        int idx = wave * 4 + i;         // 0..15
        int tile = idx >> 3;            // 0=A, 1=B
        int rg   = idx & 7;             // row-group
        const f16_t* base = tile ? (Bp + (size_t)tc * BM * BK)
                                 : (Ap + (size_t)tr * BM * BK);
        gsrc[i] = base + (size_t)(rg * 16 + lr) * BK + lc * 8;
        ldst[i] = (tile ? ldsB : ldsA) + rg * 16 * BK;   // wave-uniform base
    }

    const int m    = lane & 15;         // row within 16x16 subtile
    const int quad = lane >> 4;         // k-chunk: k = quad*8 + j
    // read-side swizzled chunk offset: phys = quad ^ ((row>>1)&3); rows are
    // s*16 + m so f depends only on m.
    const int sw8  = (quad ^ ((m >> 1) & 3)) * 8;

    // hoist epilogue norm loads off the critical tail
    float na[16], nb[4];
    #pragma unroll
    for (int i = 0; i < 4; i++) {
        #pragma unroll
        for (int r = 0; r < 4; r++)
            na[i * 4 + r] = nA[tr * BM + wm * 64 + i * 16 + quad * 4 + r];
        nb[i] = nB[tc * BM + wn * 64 + i * 16 + m];
    }

    floatx4 acc_r[4][4];
    #pragma unroll
    for (int i = 0; i < 4; i++)
        #pragma unroll
        for (int j = 0; j < 4; j++) acc_r[i][j] = (floatx4){0.f, 0.f, 0.f, 0.f};

    for (int kt = 0; kt < NKT; kt++) {
        const size_t ko = (size_t)kt * PSTRIDE;   // next packed K-panel
        __syncthreads();                 // previous compute done before overwrite
        #pragma unroll
        for (int i = 0; i < 4; i++) {
            __builtin_amdgcn_global_load_lds(
                (const __attribute__((address_space(1))) void*)(gsrc[i] + ko),
                (__attribute__((address_space(3))) void*)ldst[i],
                16, 0, 0);
        }
        __syncthreads();                 // drains vmcnt before barrier

        f16x8 ah[4], bh[4];
        #pragma unroll
        for (int s = 0; s < 4; s++) {
            ah[s] = *(const f16x8*)&ldsA[(wm * 64 + s * 16 + m) * BK + sw8];
            bh[s] = *(const f16x8*)&ldsB[(wn * 64 + s * 16 + m) * BK + sw8];
        }
        #pragma unroll
        for (int i = 0; i < 4; i++)
            #pragma unroll
            for (int j = 0; j < 4; j++)
                acc_r[i][j] = __builtin_amdgcn_mfma_f32_16x16x32_f16(ah[i], bh[j], acc_r[i][j], 0, 0, 0);
    }

    // epilogue: C/D layout col=lane&15 (B-row), row=quad*4+reg (A-row)
    const float inv_s2 = 1.0f / 2025.0f;
    float lsum = 0.f;
    #pragma unroll
    for (int i = 0; i < 4; i++)
        #pragma unroll
        for (int j = 0; j < 4; j++)
            #pragma unroll
            for (int r = 0; r < 4; r++) {
                float arg = (2.f * acc_r[i][j][r] - na[i * 4 + r] - nb[j]) * inv_s2;
                lsum += __expf(arg);
            }

    // in-wave fp64 reduce (no barriers), then 4-wave LDS combine
    double d = (double)lsum;
    #pragma unroll
    for (int off = 32; off > 0; off >>= 1) d += __shfl_down(d, off);
    if (lane == 0) wred[wave] = d;
    __syncthreads();
    if (t == 0) {
        double part = (wred[0] + wred[1] + wred[2] + wred[3]) * coef;
        // fused reduce: 64-slot device-coherent fp64 accumulate (no fences,
        // no single-address storm); vmcnt(0) orders slot-add before the
        // counter-add at the L2 coherence point (R6-verified trick).
        atomicAdd(&gsum[b & 63], part);
        asm volatile("s_waitcnt vmcnt(0)" ::: "memory");
        int old = atomicAdd(gcnt, 1);
        lastflag = (old == NBLK - 1) ? 1 : 0;
    }
    __syncthreads();
    if (lastflag && wave == 0) {
        // one wave-parallel instruction of 64 lane-atomics reads all slots
        // coherently; shuffle-reduce; single store.
        double v = atomicAdd(&gsum[lane], 0.0);
        #pragma unroll
        for (int off = 32; off > 0; off >>= 1) v += __shfl_down(v, off);
        if (lane == 0)
            out[0] = (float)(v - 1.0 / (double)(NROWS - 1)
                               - 1.0 / (double)(MROWS - 1));
    }
}

extern "C" void kernel_launch(void* const* d_in, const int* in_sizes, int n_in,
                              void* d_out, int out_size, void* d_ws, size_t ws_size,
                              hipStream_t stream) {
    const float* X = (const float*)d_in[0];   // inputs  [4096,1024] fp32
    const float* Y = (const float*)d_in[1];   // samples [4096,1024] fp32
    float* out = (float*)d_out;

    // workspace: gsum[64] | gcnt | nx | ny | Xp | Yp  (~16.7 MB)
    char* p = (char*)d_ws;
    double* gsum = (double*)p;                // 512 B
    int* gcnt = (int*)(p + 512);              p += 768;
    float* nx = (float*)p;                    p += (size_t)NROWS * sizeof(float);
    float* ny = (float*)p;                    p += (size_t)MROWS * sizeof(float);
    f16_t* Xp = (f16_t*)p;                    p += (size_t)NROWS * DDIM * sizeof(f16_t);
    f16_t* Yp = (f16_t*)p;

    convert_kernel<<<1024, 256, 0, stream>>>(X, Y, Xp, Yp, nx, ny, gsum, gcnt);
    mmd_mfma<<<NBLK, 256, 0, stream>>>(Xp, Yp, nx, ny, gsum, gcnt, out);
}

// Round 13
// 155.577 us; speedup vs baseline: 1.0320x; 1.0320x over previous
//
#include <hip/hip_runtime.h>
#include <math.h>

// MMD loss, fp16 MFMA. N=M=4096, D=1024, sigma^2=2025.
// Round 23: REVERT TO BEST-MEASURED (Round-17 kernel, 156.1us total;
// mmd 84.8us = 823 TF, MfmaUtil 35.5%, bank conflicts 0, VGPR 80).
// R12's fused-reduce falsifier fired (total>=155 => the ~70us gap is
// intrinsic: convert traffic + producer->consumer L2 handoff + fixed
// dispatch overhead; removing a launch moved cost INTO mmd, not away).
// Session ledger: every structural family probed -- deep pipelines
// (R1/R2/R3), occupancy push (R4), B-to-regs (R5/R10), fat tiles (R8),
// BK=64 (R9), atomic fusion (R6/R12) -- all regressed or tied. The two
// real wins, kept here: (a) packed K-major panels Xp/Yp[kt][row][32]
// (every glds reads 1KB contiguous); (b) true-0-conflict LDS chunk
// swizzle f(r)=((r>>1)&3) on both sides. 128^2/4-wave/TLP drain-loop,
// triangular 2080-block grid, fp64 partials, 3 launches.

typedef _Float16 f16_t;
typedef _Float16 f16x4 __attribute__((ext_vector_type(4)));
typedef _Float16 f16x8 __attribute__((ext_vector_type(8)));
typedef float floatx4 __attribute__((ext_vector_type(4)));

#define NROWS 4096
#define MROWS 4096
#define DDIM  1024
#define BM    128
#define BK    32                      // fp16 elements per K-step (64 B/row)
#define TILE  (BM * BK)               // 4096 f16 per tile (8 KB)
#define NKT   (DDIM / BK)             // 32 K-steps
#define PSTRIDE (4096 * BK)           // f16 elems per packed K-panel (256 KB)
#define NT    (NROWS / BM)            // 32 tiles per dim
#define TRI   (NT * (NT + 1) / 2)     // 528 triangular tiles
#define NBLK  (2 * TRI + NT * NT)     // 2080 blocks

// ---------------------------------------------------------------- convert
// Wave-per-row: 2048 blocks x 4 waves cover 8192 rows. Each lane loads
// 4 float4 (fully coalesced), converts to fp16, stores to the PACKED layout
// Xp[kt][row][32]: lane l, iter c covers k = c*256+l*4 -> panel c*8+(l>>3),
// pos (l&7)*4. Norm of the ROUNDED row shuffle-reduced in-wave.
__global__ __launch_bounds__(256) void convert_kernel(
    const float* __restrict__ X, const float* __restrict__ Y,
    f16_t* __restrict__ Xp, f16_t* __restrict__ Yp,
    float* __restrict__ nx, float* __restrict__ ny) {
    const int wid  = threadIdx.x >> 6;
    const int lane = threadIdx.x & 63;
    const int row  = blockIdx.x * 4 + wid;        // 0..8191
    const float* src;
    f16_t* dstp;
    float* nrm;
    int r;
    if (row < NROWS) {
        r = row;         src = X + (size_t)r * DDIM;
        dstp = Xp;  nrm = nx;
    } else {
        r = row - NROWS; src = Y + (size_t)r * DDIM;
        dstp = Yp;  nrm = ny;
    }
    const float4* s4 = (const float4*)src;        // 256 float4 per row
    float s = 0.f;
    #pragma unroll
    for (int c = 0; c < 4; c++) {
        float4 v = s4[c * 64 + lane];
        f16x4 h;
        h[0] = (f16_t)v.x; h[1] = (f16_t)v.y;
        h[2] = (f16_t)v.z; h[3] = (f16_t)v.w;
        // k = c*256 + lane*4 -> kt = c*8 + (lane>>3), pos = (lane&7)*4
        *(f16x4*)(dstp + (size_t)(c * 8 + (lane >> 3)) * PSTRIDE
                       + (size_t)r * BK + (lane & 7) * 4) = h;
        float h0 = (float)h[0], h1 = (float)h[1];
        float h2 = (float)h[2], h3 = (float)h[3];
        s += h0 * h0 + h1 * h1 + h2 * h2 + h3 * h3;
    }
    #pragma unroll
    for (int off = 32; off > 0; off >>= 1) s += __shfl_down(s, off);
    if (lane == 0) nrm[r] = s;
}

// ---------------------------------------------------------------- main GEMM
__global__ __launch_bounds__(256) void mmd_mfma(
    const f16_t* __restrict__ Xp, const f16_t* __restrict__ Yp,
    const float* __restrict__ nx, const float* __restrict__ ny,
    double* __restrict__ partials) {
    // Split A/B tiles, each BM x BK fp16 = 8 KB. Row r of a tile stores
    // logical chunk c (16 B) at phys chunk c ^ ((r>>1)&3) -- measured 0
    // bank conflicts (R7/R11).
    __shared__ __align__(16) f16_t ldsA[TILE];
    __shared__ __align__(16) f16_t ldsB[TILE];
    __shared__ double wred[4];

    const int b = blockIdx.x;
    const f16_t *Ap, *Bp;             // packed panel bases (panel 0)
    const float *nA, *nB;
    int tr, tc;
    double coef;
    if (b < 2 * TRI) {
        int u = (b < TRI) ? b : b - TRI;
        int r = 0;
        while (u >= NT - r) { u -= NT - r; r++; }
        tr = r; tc = r + u;
        double w = (tr == tc) ? 1.0 : 2.0;   // off-diagonal tiles count twice
        if (b < TRI) { Ap = Xp; Bp = Xp; nA = nx; nB = nx;
                       coef = w / ((double)NROWS * (double)(NROWS - 1)); }
        else         { Ap = Yp; Bp = Yp; nA = ny; nB = ny;
                       coef = w / ((double)MROWS * (double)(MROWS - 1)); }
    } else {
        int u = b - 2 * TRI;
        tr = u >> 5; tc = u & 31;
        Ap = Xp; Bp = Yp; nA = nx; nB = ny;
        coef = -2.0 / ((double)NROWS * (double)MROWS);
    }

    const int t    = threadIdx.x;
    const int wave = t >> 6;            // 0..3; waves 2x2: wm=wave>>1, wn=wave&1
    const int lane = t & 63;
    const int wm   = wave >> 1;
    const int wn   = wave & 1;

    // staging: 16 glds instrs (2 tiles x 8 row-groups of 16 rows); wave w
    // issues instrs w*4 .. w*4+3. Per instr: 16 rows x 64B = CONTIGUOUS 1KB
    // in the packed panel. glds writes linearly: lane l -> row lr=l>>2,
    // phys chunk l&3; lane fetches global chunk (l&3)^((l>>3)&3) so phys
    // chunk p of row r holds logical p^((r>>1)&3).
    const int lr = lane >> 2;           // 0..15 within row-group
    const int lc = (lane & 3) ^ ((lane >> 3) & 3);
    const f16_t* gsrc[4];
    f16_t* ldst[4];
    #pragma unroll
    for (int i = 0; i < 4; i++) {
        int idx = wave * 4 + i;         // 0..15
        int tile = idx >> 3;            // 0=A, 1=B
        int rg   = idx & 7;             // row-group
        const f16_t* base = tile ? (Bp + (size_t)tc * BM * BK)
                                 : (Ap + (size_t)tr * BM * BK);
        gsrc[i] = base + (size_t)(rg * 16 + lr) * BK + lc * 8;
        ldst[i] = (tile ? ldsB : ldsA) + rg * 16 * BK;   // wave-uniform base
    }

    const int m    = lane & 15;         // row within 16x16 subtile
    const int quad = lane >> 4;         // k-chunk: k = quad*8 + j
    // read-side swizzled chunk offset: phys = quad ^ ((row>>1)&3); rows are
    // s*16 + m so f depends only on m.
    const int sw8  = (quad ^ ((m >> 1) & 3)) * 8;

    // hoist epilogue norm loads off the critical tail
    float na[16], nb[4];
    #pragma unroll
    for (int i = 0; i < 4; i++) {
        #pragma unroll
        for (int r = 0; r < 4; r++)
            na[i * 4 + r] = nA[tr * BM + wm * 64 + i * 16 + quad * 4 + r];
        nb[i] = nB[tc * BM + wn * 64 + i * 16 + m];
    }

    floatx4 acc_r[4][4];
    #pragma unroll
    for (int i = 0; i < 4; i++)
        #pragma unroll
        for (int j = 0; j < 4; j++) acc_r[i][j] = (floatx4){0.f, 0.f, 0.f, 0.f};

    for (int kt = 0; kt < NKT; kt++) {
        const size_t ko = (size_t)kt * PSTRIDE;   // next packed K-panel
        __syncthreads();                 // previous compute done before overwrite
        #pragma unroll
        for (int i = 0; i < 4; i++) {
            __builtin_amdgcn_global_load_lds(
                (const __attribute__((address_space(1))) void*)(gsrc[i] + ko),
                (__attribute__((address_space(3))) void*)ldst[i],
                16, 0, 0);
        }
        __syncthreads();                 // drains vmcnt before barrier

        f16x8 ah[4], bh[4];
        #pragma unroll
        for (int s = 0; s < 4; s++) {
            ah[s] = *(const f16x8*)&ldsA[(wm * 64 + s * 16 + m) * BK + sw8];
            bh[s] = *(const f16x8*)&ldsB[(wn * 64 + s * 16 + m) * BK + sw8];
        }
        #pragma unroll
        for (int i = 0; i < 4; i++)
            #pragma unroll
            for (int j = 0; j < 4; j++)
                acc_r[i][j] = __builtin_amdgcn_mfma_f32_16x16x32_f16(ah[i], bh[j], acc_r[i][j], 0, 0, 0);
    }

    // epilogue: C/D layout col=lane&15 (B-row), row=quad*4+reg (A-row)
    const float inv_s2 = 1.0f / 2025.0f;
    float lsum = 0.f;
    #pragma unroll
    for (int i = 0; i < 4; i++)
        #pragma unroll
        for (int j = 0; j < 4; j++)
            #pragma unroll
            for (int r = 0; r < 4; r++) {
                float arg = (2.f * acc_r[i][j][r] - na[i * 4 + r] - nb[j]) * inv_s2;
                lsum += __expf(arg);
            }

    // in-wave fp64 reduce (no barriers), then 4-wave LDS combine; plain store
    double d = (double)lsum;
    #pragma unroll
    for (int off = 32; off > 0; off >>= 1) d += __shfl_down(d, off);
    if (lane == 0) wred[wave] = d;
    __syncthreads();
    if (t == 0)
        partials[b] = (wred[0] + wred[1] + wred[2] + wred[3]) * coef;
}

__global__ __launch_bounds__(256) void final_reduce(const double* __restrict__ partials,
                                                    float* __restrict__ out) {
    __shared__ double red[256];
    int t = threadIdx.x;
    double s = 0.0;
    for (int i = t; i < NBLK; i += 256) s += partials[i];
    red[t] = s;
    __syncthreads();
    for (int off = 128; off > 0; off >>= 1) {
        if (t < off) red[t] += red[t + off];
        __syncthreads();
    }
    if (t == 0) {
        // analytic diagonal subtraction: 1/(n-1) + 1/(m-1)
        double mmd = red[0] - 1.0 / (double)(NROWS - 1) - 1.0 / (double)(MROWS - 1);
        out[0] = (float)mmd;
    }
}

extern "C" void kernel_launch(void* const* d_in, const int* in_sizes, int n_in,
                              void* d_out, int out_size, void* d_ws, size_t ws_size,
                              hipStream_t stream) {
    const float* X = (const float*)d_in[0];   // inputs  [4096,1024] fp32
    const float* Y = (const float*)d_in[1];   // samples [4096,1024] fp32
    float* out = (float*)d_out;

    // workspace: partials | nx | ny | Xp | Yp  (~16.7 MB)
    char* p = (char*)d_ws;
    double* partials = (double*)p;            p += ((size_t)NBLK * sizeof(double) + 255) & ~255ULL;
    float* nx = (float*)p;                    p += (size_t)NROWS * sizeof(float);
    float* ny = (float*)p;                    p += (size_t)MROWS * sizeof(float);
    f16_t* Xp = (f16_t*)p;                    p += (size_t)NROWS * DDIM * sizeof(f16_t);
    f16_t* Yp = (f16_t*)p;

    convert_kernel<<<(NROWS + MROWS) / 4, 256, 0, stream>>>(X, Y, Xp, Yp, nx, ny);
    mmd_mfma<<<NBLK, 256, 0, stream>>>(Xp, Yp, nx, ny, partials);
    final_reduce<<<1, 256, 0, stream>>>(partials, out);
}